// Round 6
// baseline (3309.695 us; speedup 1.0000x reference)
//
#include <hip/hip_runtime.h>
#include <cstddef>
#include <cstdint>

typedef unsigned short u16;
typedef short bf16x8 __attribute__((ext_vector_type(8)));
typedef float f32x4 __attribute__((ext_vector_type(4)));

__device__ __forceinline__ float gelu_tanh(float x) {
  float x3 = x * x * x;
  float t = tanhf(0.7978845608028654f * (x + 0.044715f * x3));
  return 0.5f * x * (1.0f + t);
}
__device__ __forceinline__ float softplus_f(float x) {
  return (x > 20.0f) ? x : log1pf(expf(x));
}
__device__ __forceinline__ u16 f2bf(float f) {
  uint32_t u = __float_as_uint(f);
  uint32_t r = (u + 0x7fffu + ((u >> 16) & 1u)) >> 16;
  return (u16)r;
}

// async global->LDS, 16B/lane; LDS dest = wave-uniform base + lane*16
__device__ __forceinline__ void gload16(const u16* g, u16* l) {
  __builtin_amdgcn_global_load_lds(
      (const __attribute__((address_space(1))) void*)g,
      (__attribute__((address_space(3))) void*)l, 16, 0, 0);
}

// ==================== unified MFMA GEMM, 128xTN tile, two-panel BK=64 ====================
// A [M][K] bf16 row-major; Bt [N][K] bf16.  XCD-swizzled block order.
// MODE 0: Cf = v              MODE 1: Cb = bf16(gelu(v))
// MODE 2: Cf += v             MODE 3: decoder scatter out = v + bias
// MODE 4: Cf += v + Df        MODE 5: Cf += v; Cb = bf16(Cf)
template <int TN, int MODE>
__global__ __launch_bounds__(256) void gemm_kernel(
    const u16* __restrict__ A, const u16* __restrict__ Bt, int K, int ldc,
    float* __restrict__ Cf, u16* __restrict__ Cb,
    const float* __restrict__ bias, const float* __restrict__ Df) {
  __shared__ u16 As[2][128 * 32];
  __shared__ u16 Bs[2][TN * 32];
  constexpr int NI = (TN == 64) ? 2 : 4;
  // XCD-aware swizzle: cluster same-n blocks onto the same XCD (grid total % 8 == 0)
  const int total8 = (gridDim.x * gridDim.y) >> 3;
  const int lid = blockIdx.x + gridDim.x * blockIdx.y;
  const int gsw = (lid & 7) * total8 + (lid >> 3);
  const int m0 = (gsw % gridDim.x) * 128, n0 = (gsw / gridDim.x) * TN;
  const int tid = threadIdx.x;
  const int lane = tid & 63, w = tid >> 6;
  const int lane15 = lane & 15, quad = lane >> 4;
  const int r0 = lane >> 2, e0 = (lane & 3) * 8;
  const int wy = (TN == 64) ? w : (w >> 1);
  const int wx = (TN == 64) ? 0 : (w & 1);

  const u16* ag0 = A + (size_t)(m0 + w * 32 + r0) * K + e0;
  const u16* ag1 = ag0 + (size_t)16 * K;
  const u16* bg0 = (TN == 64) ? Bt + (size_t)(n0 + w * 16 + r0) * K + e0
                              : Bt + (size_t)(n0 + w * 32 + r0) * K + e0;
  const u16* bg1 = bg0 + (size_t)16 * K;

  f32x4 acc[NI][4] = {};
  const int abase = (wy * (16 * NI) + lane15) * 32 + quad * 8;
  const int bbase = (wx * 64 + lane15) * 32 + quad * 8;

  for (int k0 = 0; k0 < K; k0 += 64) {
#pragma unroll
    for (int p = 0; p < 2; ++p) {
      const int kk = k0 + 32 * p;
      gload16(ag0 + kk, &As[p][w * 1024]);
      gload16(ag1 + kk, &As[p][w * 1024 + 512]);
      if (TN == 64) {
        gload16(bg0 + kk, &Bs[p][w * 512]);
      } else {
        gload16(bg0 + kk, &Bs[p][w * 1024]);
        gload16(bg1 + kk, &Bs[p][w * 1024 + 512]);
      }
    }
    __syncthreads();
#pragma unroll
    for (int p = 0; p < 2; ++p) {
      bf16x8 af[NI], bf[4];
#pragma unroll
      for (int i = 0; i < NI; ++i) af[i] = *(const bf16x8*)&As[p][abase + i * 16 * 32];
#pragma unroll
      for (int j = 0; j < 4; ++j) bf[j] = *(const bf16x8*)&Bs[p][bbase + j * 16 * 32];
#pragma unroll
      for (int i = 0; i < NI; ++i)
#pragma unroll
        for (int j = 0; j < 4; ++j)
          acc[i][j] = __builtin_amdgcn_mfma_f32_16x16x32_bf16(af[i], bf[j], acc[i][j], 0, 0, 0);
    }
    __syncthreads();
  }

  const int mw = m0 + wy * (16 * NI), nw = n0 + wx * 64;
#pragma unroll
  for (int i = 0; i < NI; ++i) {
#pragma unroll
    for (int j = 0; j < 4; ++j) {
      const int col = nw + j * 16 + lane15;
#pragma unroll
      for (int r = 0; r < 4; ++r) {
        const int row = mw + i * 16 + quad * 4 + r;
        const float v = acc[i][j][r];
        const size_t idx = (size_t)row * ldc + col;
        if (MODE == 0) {
          Cf[idx] = v;
        } else if (MODE == 1) {
          Cb[idx] = f2bf(gelu_tanh(v));
        } else if (MODE == 2) {
          Cf[idx] += v;
        } else if (MODE == 3) {
          const int frame = row >> 8, pix = row & 255;
          const int hp = pix >> 4, wp = pix & 15;
          const int co = col >> 8, p1 = (col >> 4) & 15, p2 = col & 15;
          Cf[(((size_t)frame * 4 + co) * 256 + hp * 16 + p1) * 256 + wp * 16 + p2] = v + bias[col];
        } else if (MODE == 4) {
          Cf[idx] += v + Df[idx];
        } else if (MODE == 5) {
          const float nz = Cf[idx] + v;
          Cf[idx] = nz;
          Cb[idx] = f2bf(nz);
        }
      }
    }
  }
}

// ==================== conv3x3 implicit-GEMM, 128x128 tile, 3-way tap-split ====================
// grid (96,6,3): zi-th split computes taps [3zi,3zi+3) and atomicAdds into z.
// Bias folded into split 0. XCD-swizzled so each XCD's blocks share (zi,n) B-slices.
__global__ __launch_bounds__(256) void conv_mfma_kernel(
    const u16* __restrict__ xnp, const u16* __restrict__ Btc,
    const float* __restrict__ cbias, float* __restrict__ z) {
  __shared__ u16 As[2][128 * 32];
  __shared__ u16 Bs[2][128 * 32];
  const int lid = blockIdx.x + 96 * (blockIdx.y + 6 * blockIdx.z);  // 0..1727
  const int gsw = (lid & 7) * 216 + (lid >> 3);
  const int zi = gsw / 576;
  const int rem = gsw - zi * 576;
  const int m0 = (rem % 96) * 128, n0 = (rem / 96) * 128;
  const int tid = threadIdx.x;
  const int lane = tid & 63, w = tid >> 6;
  const int lane15 = lane & 15, quad = lane >> 4;
  const int r0 = lane >> 2, e0 = (lane & 3) * 8;

  const int rowA0 = m0 + w * 32 + r0, rowA1 = rowA0 + 16;
  const long long cen0 = ((long long)(rowA0 >> 8) * 324 + ((((rowA0 & 255) >> 4) + 1) * 18) + (rowA0 & 15) + 1) * 768 + e0;
  const long long cen1 = ((long long)(rowA1 >> 8) * 324 + ((((rowA1 & 255) >> 4) + 1) * 18) + (rowA1 & 15) + 1) * 768 + e0;
  const u16* bg0 = Btc + (size_t)(n0 + w * 32 + r0) * 6912 + e0;
  const u16* bg1 = bg0 + (size_t)16 * 6912;

  f32x4 acc[4][4] = {};
  const int wy = w >> 1, wx = w & 1;
  const int abase = (wy * 64 + lane15) * 32 + quad * 8;
  const int bbase = (wx * 64 + lane15) * 32 + quad * 8;

  for (int tap = 3 * zi; tap < 3 * zi + 3; ++tap) {
    const int doff = ((tap / 3 - 1) * 18 + (tap % 3 - 1)) * 768;
    const u16* a0 = xnp + cen0 + doff;
    const u16* a1 = xnp + cen1 + doff;
    const u16* b0 = bg0 + tap * 768;
    const u16* b1 = bg1 + tap * 768;
    for (int kc = 0; kc < 768; kc += 64) {
#pragma unroll
      for (int p = 0; p < 2; ++p) {
        const int kk = kc + 32 * p;
        gload16(a0 + kk, &As[p][w * 1024]);
        gload16(a1 + kk, &As[p][w * 1024 + 512]);
        gload16(b0 + kk, &Bs[p][w * 1024]);
        gload16(b1 + kk, &Bs[p][w * 1024 + 512]);
      }
      __syncthreads();
#pragma unroll
      for (int p = 0; p < 2; ++p) {
        bf16x8 af[4], bf[4];
#pragma unroll
        for (int i = 0; i < 4; ++i) af[i] = *(const bf16x8*)&As[p][abase + i * 16 * 32];
#pragma unroll
        for (int j = 0; j < 4; ++j) bf[j] = *(const bf16x8*)&Bs[p][bbase + j * 16 * 32];
#pragma unroll
        for (int i = 0; i < 4; ++i)
#pragma unroll
          for (int j = 0; j < 4; ++j)
            acc[i][j] = __builtin_amdgcn_mfma_f32_16x16x32_bf16(af[i], bf[j], acc[i][j], 0, 0, 0);
      }
      __syncthreads();
    }
  }

  const int mw = m0 + wy * 64, nw = n0 + wx * 64;
#pragma unroll
  for (int i = 0; i < 4; ++i) {
#pragma unroll
    for (int j = 0; j < 4; ++j) {
      const int col = nw + j * 16 + lane15;
      const float bv = (zi == 0) ? cbias[col] : 0.0f;
#pragma unroll
      for (int r = 0; r < 4; ++r) {
        const int row = mw + i * 16 + quad * 4 + r;
        atomicAdd(&z[(size_t)row * 768 + col], acc[i][j][r] + bv);
      }
    }
  }
}

// ==================== encoder: patch-embed MFMA (fp32->bf16 staging, runs once) ====================
__global__ __launch_bounds__(256) void encoder_mfma_kernel(
    const float* __restrict__ x, const float* __restrict__ ew,
    const float* __restrict__ eb, float* __restrict__ z) {
  __shared__ u16 As[128 * 32];
  __shared__ u16 Bs[128 * 32];
  const int m0 = blockIdx.x * 128, n0 = blockIdx.y * 128;
  const int tid = threadIdx.x;
  const int lane = tid & 63, w = tid >> 6;
  const int lane15 = lane & 15, quad = lane >> 4;
  const int srow = tid >> 1, half = tid & 1;
  const int arow = m0 + srow;
  const int frame = arow >> 8, pix = arow & 255, hh = pix >> 4, ww = pix & 15;

  f32x4 acc[4][4] = {};
  const int wy = w >> 1, wx = w & 1;
  const int ar_base = (wy * 64 + lane15) * 32 + quad * 8;
  const int br_base = (wx * 64 + lane15) * 32 + quad * 8;

  for (int k0 = 0; k0 < 1024; k0 += 32) {
    const int gk = k0 + half * 16;
    const int c = gk >> 8, ph = (gk >> 4) & 15;
    const float* ax = x + (((size_t)(frame * 4 + c) * 256 + hh * 16 + ph) * 256 + ww * 16);
    const float* bx = ew + (size_t)(n0 + srow) * 1024 + gk;
    u16 ta[16], tb[16];
#pragma unroll
    for (int j = 0; j < 4; ++j) {
      const float4 va = *(const float4*)(ax + j * 4);
      const float4 vb = *(const float4*)(bx + j * 4);
      ta[j * 4 + 0] = f2bf(va.x); ta[j * 4 + 1] = f2bf(va.y);
      ta[j * 4 + 2] = f2bf(va.z); ta[j * 4 + 3] = f2bf(va.w);
      tb[j * 4 + 0] = f2bf(vb.x); tb[j * 4 + 1] = f2bf(vb.y);
      tb[j * 4 + 2] = f2bf(vb.z); tb[j * 4 + 3] = f2bf(vb.w);
    }
    __syncthreads();
    *(uint4*)&As[srow * 32 + half * 16] = *(uint4*)ta;
    *(uint4*)&As[srow * 32 + half * 16 + 8] = *(uint4*)(ta + 8);
    *(uint4*)&Bs[srow * 32 + half * 16] = *(uint4*)tb;
    *(uint4*)&Bs[srow * 32 + half * 16 + 8] = *(uint4*)(tb + 8);
    __syncthreads();
    bf16x8 af[4], bfv[4];
#pragma unroll
    for (int i = 0; i < 4; ++i) af[i] = *(const bf16x8*)&As[ar_base + i * 16 * 32];
#pragma unroll
    for (int j = 0; j < 4; ++j) bfv[j] = *(const bf16x8*)&Bs[br_base + j * 16 * 32];
#pragma unroll
    for (int i = 0; i < 4; ++i)
#pragma unroll
      for (int j = 0; j < 4; ++j)
        acc[i][j] = __builtin_amdgcn_mfma_f32_16x16x32_bf16(af[i], bfv[j], acc[i][j], 0, 0, 0);
  }

  const int mw = m0 + wy * 64, nw = n0 + wx * 64;
#pragma unroll
  for (int i = 0; i < 4; ++i)
#pragma unroll
    for (int j = 0; j < 4; ++j) {
      const int col = nw + j * 16 + lane15;
      const float bv = eb[col];
#pragma unroll
      for (int r = 0; r < 4; ++r) {
        const int row = mw + i * 16 + quad * 4 + r;
        z[(size_t)row * 768 + col] = acc[i][j][r] + bv;
      }
    }
}

// ==================== weight prep ====================
__global__ __launch_bounds__(256) void expand_kernel(
    const float* __restrict__ Wre, const float* __restrict__ Wim,
    int ldw, int Kc, int Nc, u16* __restrict__ Wt) {
  __shared__ float tile[32][33];
  const int k0 = blockIdx.x * 32, n0 = blockIdx.y * 32;
  const bool khi = k0 >= Kc, nhi = n0 >= Nc;
  const float* src = (khi != nhi) ? Wim : Wre;
  const float sgn = (!nhi && khi) ? -1.0f : 1.0f;
  const int sk = k0 - (khi ? Kc : 0), sn = n0 - (nhi ? Nc : 0);
  const int c = threadIdx.x & 31, r8 = threadIdx.x >> 5;
  for (int r = r8; r < 32; r += 8)
    tile[r][c] = src[(size_t)(sk + r) * ldw + sn + c];
  __syncthreads();
  const int twoK = 2 * Kc;
  for (int r = r8; r < 32; r += 8)
    Wt[(size_t)(n0 + r) * twoK + k0 + c] = f2bf(sgn * tile[c][r]);
}

__global__ __launch_bounds__(256) void reorder_cw_kernel(
    const float* __restrict__ cwl, u16* __restrict__ Btc) {
  __shared__ float buf[6912];
  const int o = blockIdx.x;
  const float* src = cwl + (size_t)o * 6912;
  for (int i = threadIdx.x; i < 6912; i += 256) buf[i] = src[i];
  __syncthreads();
  u16* dst = Btc + (size_t)o * 6912;
  for (int i = threadIdx.x; i < 6912; i += 256) {
    const int tap = i / 768, cc = i - tap * 768;
    dst[i] = f2bf(buf[cc * 9 + tap]);
  }
}

__global__ __launch_bounds__(256) void cast_bf16_kernel(
    const float* __restrict__ in, u16* __restrict__ out, int n) {
  const int g = blockIdx.x * 256 + threadIdx.x;
  if (g < n) out[g] = f2bf(in[g]);
}

// vectorized fp32->bf16 cast (4 elems/thread)
__global__ __launch_bounds__(256) void cast_bf16x4_kernel(
    const float* __restrict__ in, u16* __restrict__ out, int n4) {
  const int g = blockIdx.x * 256 + threadIdx.x;
  if (g < n4) {
    const float4 v = *(const float4*)(in + (size_t)g * 4);
    u16 p[4] = {f2bf(v.x), f2bf(v.y), f2bf(v.z), f2bf(v.w)};
    *(uint2*)(out + (size_t)g * 4) = *(uint2*)p;
  }
}

// ==================== LayerNorm (contiguous 768) ====================
template <bool HALO>
__global__ __launch_bounds__(192) void ln_kernel(
    const float* __restrict__ in, const float* __restrict__ g,
    const float* __restrict__ b, u16* __restrict__ out) {
  const int row = blockIdx.x, tid = threadIdx.x;
  const float4 v = *(const float4*)(in + (size_t)row * 768 + tid * 4);
  float s = v.x + v.y + v.z + v.w;
  float q = v.x * v.x + v.y * v.y + v.z * v.z + v.w * v.w;
#pragma unroll
  for (int off = 32; off > 0; off >>= 1) {
    s += __shfl_down(s, off);
    q += __shfl_down(q, off);
  }
  __shared__ float rs[3], rq[3];
  if ((tid & 63) == 0) { rs[tid >> 6] = s; rq[tid >> 6] = q; }
  __syncthreads();
  const float S = rs[0] + rs[1] + rs[2], Q = rq[0] + rq[1] + rq[2];
  const float mean = S * (1.0f / 768.0f);
  const float inv = rsqrtf(Q * (1.0f / 768.0f) - mean * mean + 1e-5f);
  const float4 gv = *(const float4*)(g + tid * 4);
  const float4 bv = *(const float4*)(b + tid * 4);
  u16 p[4];
  p[0] = f2bf((v.x - mean) * inv * gv.x + bv.x);
  p[1] = f2bf((v.y - mean) * inv * gv.y + bv.y);
  p[2] = f2bf((v.z - mean) * inv * gv.z + bv.z);
  p[3] = f2bf((v.w - mean) * inv * gv.w + bv.w);
  size_t base;
  if (HALO) {
    const int f = row >> 8, pp = row & 255, h = pp >> 4, ww = pp & 15;
    base = ((size_t)f * 324 + (h + 1) * 18 + ww + 1) * 768;
  } else {
    base = (size_t)row * 768;
  }
  *(uint2*)(out + base + tid * 4) = *(uint2*)p;
}

// ==================== mean over 256 pixels ====================
__global__ __launch_bounds__(768) void mean_kernel(
    const float* __restrict__ eig, float* __restrict__ mr, float* __restrict__ mi) {
  const int f = blockIdx.x, c = threadIdx.x;
  const float* p = eig + (size_t)f * 256 * 768 + c;
  float s0 = 0.f, s1 = 0.f, s2 = 0.f, s3 = 0.f;
  for (int px = 0; px < 256; px += 4) {
    s0 += p[(size_t)px * 768];
    s1 += p[(size_t)(px + 1) * 768];
    s2 += p[(size_t)(px + 2) * 768];
    s3 += p[(size_t)(px + 3) * 768];
  }
  const float tot = (s0 + s1 + s2 + s3) * (1.0f / 256.0f);
  if (c < 384) mr[f * 384 + c] = tot;
  else         mi[f * 384 + c - 384] = tot;
}

// ==================== flux scan + operator precompute ====================
__global__ __launch_bounds__(384) void flux_kernel(
    const float* __restrict__ dt, const float* __restrict__ lamf,
    const float* __restrict__ nu, const float* __restrict__ omega,
    const float* __restrict__ mr, const float* __restrict__ mi,
    float* __restrict__ fluxr, float* __restrict__ fluxi,
    float* __restrict__ opdr, float* __restrict__ opdi,
    float* __restrict__ opfr, float* __restrict__ opfi) {
  const int b = blockIdx.x;
  const int d = threadIdx.x;
  const float sp = softplus_f(lamf[d]);
  float lre = -softplus_f(nu[d]);
  lre = fmaxf(lre, -5.0f);
  const float lim = omega[d];
  const float den = lre * lre + lim * lim;
  float fr = 0.f, fi = 0.f;
  for (int t = 0; t < 12; ++t) {
    const float dtv = dt[b * 12 + t];
    const int idx = (b * 12 + t) * 384 + d;
    const float A = expf(-sp * dtv);
    fr = A * fr + mr[idx] * dtv;
    fi = A * fi + mi[idx] * dtv;
    fluxr[idx] = fr; fluxi[idx] = fi;
    const float ed = expf(lre * dtv);
    const float odr = ed * cosf(lim * dtv);
    const float odi = ed * sinf(lim * dtv);
    opdr[idx] = odr; opdi[idx] = odi;
    const float nr_ = odr - 1.0f, ni_ = odi;
    opfr[idx] = (nr_ * lre + ni_ * lim) / den;
    opfi[idx] = (ni_ * lre - nr_ * lim) / den;
  }
}

// ==================== small fp32 complex GEMM + gate-product epilogue ====================
#define SBM 64
#define SBN 64
#define SBK 32
__global__ __launch_bounds__(256) void cgemm_src_kernel(
    const float* __restrict__ Ar, const float* __restrict__ Ai, int lda,
    const float* __restrict__ Wr, const float* __restrict__ Wi, int ldw,
    const float* __restrict__ Wg,
    float* __restrict__ G, float* __restrict__ SGr, float* __restrict__ SGi,
    int ldc, int M, int K) {
  __shared__ float Asr[SBK][SBM], Asi[SBK][SBM];
  __shared__ float Wsr[SBK][SBN], Wsi[SBK][SBN];
  const int m0 = blockIdx.x * SBM;
  const int n0 = blockIdx.y * SBN;
  const int tid = threadIdx.x;
  const int tn = tid & 15, tm = tid >> 4;
  float accr[4][4] = {}, acci[4][4] = {};
  for (int k0 = 0; k0 < K; k0 += SBK) {
    for (int s = tid; s < 512; s += 256) {
      {
        int r = s >> 3, kk = (s & 7) << 2;
        int row = m0 + r;
        float4 vr = {0.f, 0.f, 0.f, 0.f}, vi = {0.f, 0.f, 0.f, 0.f};
        if (row < M) {
          vr = *(const float4*)(Ar + (size_t)row * lda + k0 + kk);
          vi = *(const float4*)(Ai + (size_t)row * lda + k0 + kk);
        }
        Asr[kk + 0][r] = vr.x; Asr[kk + 1][r] = vr.y; Asr[kk + 2][r] = vr.z; Asr[kk + 3][r] = vr.w;
        Asi[kk + 0][r] = vi.x; Asi[kk + 1][r] = vi.y; Asi[kk + 2][r] = vi.z; Asi[kk + 3][r] = vi.w;
      }
      {
        int wr_ = s >> 4, wc = (s & 15) << 2;
        *(float4*)&Wsr[wr_][wc] = *(const float4*)(Wr + (size_t)(k0 + wr_) * ldw + n0 + wc);
        *(float4*)&Wsi[wr_][wc] = *(const float4*)(Wi + (size_t)(k0 + wr_) * ldw + n0 + wc);
      }
    }
    __syncthreads();
#pragma unroll
    for (int kk = 0; kk < SBK; ++kk) {
      float4 ar4 = *(const float4*)&Asr[kk][tm << 2];
      float4 ai4 = *(const float4*)&Asi[kk][tm << 2];
      float4 wr4 = *(const float4*)&Wsr[kk][tn << 2];
      float4 wi4 = *(const float4*)&Wsi[kk][tn << 2];
      float ar[4] = {ar4.x, ar4.y, ar4.z, ar4.w};
      float ai[4] = {ai4.x, ai4.y, ai4.z, ai4.w};
      float wr[4] = {wr4.x, wr4.y, wr4.z, wr4.w};
      float wi[4] = {wi4.x, wi4.y, wi4.z, wi4.w};
#pragma unroll
      for (int i = 0; i < 4; ++i)
#pragma unroll
        for (int j = 0; j < 4; ++j) {
          accr[i][j] = fmaf(ar[i], wr[j], accr[i][j]);
          accr[i][j] = fmaf(-ai[i], wi[j], accr[i][j]);
          acci[i][j] = fmaf(ar[i], wi[j], acci[i][j]);
          acci[i][j] = fmaf(ai[i], wr[j], acci[i][j]);
        }
    }
    __syncthreads();
  }
#pragma unroll
  for (int i = 0; i < 4; ++i) {
    int row = m0 + (tm << 2) + i;
    if (row >= M) continue;
#pragma unroll
    for (int j = 0; j < 4; ++j) {
      int col = n0 + (tn << 2) + j;
      size_t idx = (size_t)row * ldc + col;
      const float gate = 1.0f / (1.0f + expf(-Ar[idx] * Wg[col]));
      G[idx] = gate;
      SGr[idx] = accr[i][j] * (1.0f - gate);
      SGi[idx] = acci[i][j] * (1.0f - gate);
    }
  }
}

// ==================== fused forcing + u_out pscan -> bf16 ub ====================
__global__ __launch_bounds__(256) void pscan_fused_kernel(
    const float* __restrict__ eig,
    const float* __restrict__ Gv,
    const float* __restrict__ SGr, const float* __restrict__ SGi,
    const float* __restrict__ opfr, const float* __restrict__ opfi,
    const float* __restrict__ opdr, const float* __restrict__ opdi,
    u16* __restrict__ ub) {
  const int g = blockIdx.x * 256 + threadIdx.x;
  if (g >= 4 * 256 * 384) return;
  const int d = g % 384;
  const int pix = (g / 384) & 255;
  const int b = g / (384 * 256);
  float ur = 0.f, ui = 0.f;
  for (int t = 0; t < 12; ++t) {
    const int frame = b * 12 + t;
    const size_t idx = ((size_t)frame * 256 + pix) * 768 + d;
    const int fidx = frame * 384 + d;
    const float G = Gv[fidx];
    const float fr = eig[idx] * G + SGr[fidx];
    const float fi = eig[idx + 384] * G + SGi[fidx];
    const float pr = opfr[fidx], pi = opfi[fidx];
    const float utr = fr * pr - fi * pi;
    const float uti = fr * pi + fi * pr;
    const float ar = opdr[fidx], ai = opdi[fidx];
    const float nr = ar * ur - ai * ui + utr;
    const float ni = ar * ui + ai * ur + uti;
    ub[idx] = f2bf(nr); ub[idx + 384] = f2bf(ni);
    ur = nr; ui = ni;
  }
}

extern "C" void kernel_launch(void* const* d_in, const int* in_sizes, int n_in,
                              void* d_out, int out_size, void* d_ws, size_t ws_size,
                              hipStream_t stream) {
  const float* x        = (const float*)d_in[0];
  const float* dt       = (const float*)d_in[1];
  const float* enc_w    = (const float*)d_in[2];
  const float* enc_b    = (const float*)d_in[3];
  const float* ns_g     = (const float*)d_in[4];
  const float* ns_b     = (const float*)d_in[5];
  const float* cw       = (const float*)d_in[6];
  const float* cb       = (const float*)d_in[7];
  const float* nt_g     = (const float*)d_in[8];
  const float* nt_b     = (const float*)d_in[9];
  const float* E_re     = (const float*)d_in[10];
  const float* E_im     = (const float*)d_in[11];
  const float* Ei_re    = (const float*)d_in[12];
  const float* Ei_im    = (const float*)d_in[13];
  const float* lam_flux = (const float*)d_in[14];
  const float* Ws_re    = (const float*)d_in[15];
  const float* Ws_im    = (const float*)d_in[16];
  const float* Wg       = (const float*)d_in[17];
  const float* nu       = (const float*)d_in[18];
  const float* omega    = (const float*)d_in[19];
  const float* w1_re    = (const float*)d_in[20];
  const float* w1_im    = (const float*)d_in[21];
  const float* w2_re    = (const float*)d_in[22];
  const float* w2_im    = (const float*)d_in[23];
  const float* dec_w    = (const float*)d_in[24];
  const float* dec_b    = (const float*)d_in[25];
  float* out = (float*)d_out;

  const size_t NPF = 12288ull * 768;        // 9,437,184
  const size_t XNP = 48ull * 324 * 768;     // 11,943,936 (halo-padded plane)
  const size_t SM = 48ull * 384;

  float* z   = (float*)d_ws;                 // [12288][768] fp32 residual master
  float* eig = z + NPF;                      // fp32; aliased by h1b
  float* df  = eig + NPF;                    // fp32; aliased by zb
  u16* xnp   = (u16*)(df + NPF);             // halo xnbp / flat xnb / ub
  u16* Btc   = xnp + XNP;                    // [768][6912]
  u16* Et    = Btc + 5308416;                // [768][768]
  u16* Eit   = Et + 589824;
  u16* W1t   = Eit + 589824;                 // 2 chunks x [1536][768]
  u16* W2t   = W1t + 2359296;                // 2 chunks x [768][1536]
  u16* dwt   = W2t + 2359296;                // [1024][768]
  float* sm  = (float*)(dwt + 786432);
  float* mr    = sm;            float* mi    = mr + SM;
  float* fluxr = mi + SM;       float* fluxi = fluxr + SM;
  float* opdr  = fluxi + SM;    float* opdi  = opdr + SM;
  float* opfr  = opdi + SM;     float* opfi  = opfr + SM;
  float* Gv    = opfi + SM;     float* SGr   = Gv + SM;
  float* SGi   = SGr + SM;

  const size_t need = ((char*)(SGi + SM)) - ((char*)d_ws);
  if (ws_size < need) return;

  u16* zb  = (u16*)df;    // bf16 shadow of z (df dead at that point)
  u16* h1b = (u16*)eig;   // FFN hidden chunk [12288][1536] bf16 (eig dead after pscan)

  cast_bf16_kernel<<<(786432 + 255) / 256, 256, 0, stream>>>(dec_w, dwt, 786432);
  encoder_mfma_kernel<<<dim3(96, 6), 256, 0, stream>>>(x, enc_w, enc_b, z);

  for (int l = 0; l < 4; ++l) {
    const size_t DD = 384ull * 384, DF = 384ull * 1536;
    hipMemsetAsync(xnp, 0, XNP * sizeof(u16), stream);  // zero halo borders
    reorder_cw_kernel<<<768, 256, 0, stream>>>(cw + (size_t)l * 768 * 768 * 9, Btc);
    expand_kernel<<<dim3(24, 24), 256, 0, stream>>>(E_re + l * DD, E_im + l * DD, 384, 384, 384, Et);
    expand_kernel<<<dim3(24, 24), 256, 0, stream>>>(Ei_re + l * DD, Ei_im + l * DD, 384, 384, 384, Eit);
    for (int ch = 0; ch < 2; ++ch) {
      expand_kernel<<<dim3(24, 48), 256, 0, stream>>>(
          w1_re + l * DF + ch * 768, w1_im + l * DF + ch * 768, 1536, 384, 768, W1t + (size_t)ch * 1179648);
      expand_kernel<<<dim3(48, 24), 256, 0, stream>>>(
          w2_re + l * DF + (size_t)ch * 768 * 384, w2_im + l * DF + (size_t)ch * 768 * 384, 384, 768, 384,
          W2t + (size_t)ch * 1179648);
    }

    ln_kernel<true><<<12288, 192, 0, stream>>>(z, ns_g + l * 768, ns_b + l * 768, xnp);
    conv_mfma_kernel<<<dim3(96, 6, 3), 256, 0, stream>>>(xnp, Btc, cb + l * 768, z);
    cast_bf16x4_kernel<<<(int)((NPF / 4 + 255) / 256), 256, 0, stream>>>(z, zb, (int)(NPF / 4));
    gemm_kernel<64, 0><<<dim3(96, 12), 256, 0, stream>>>(zb, Et, 768, 768, eig, nullptr, nullptr, nullptr);
    mean_kernel<<<48, 768, 0, stream>>>(eig, mr, mi);
    flux_kernel<<<4, 384, 0, stream>>>(dt, lam_flux + l * 384, nu + l * 384, omega + l * 384,
                                       mr, mi, fluxr, fluxi, opdr, opdi, opfr, opfi);
    cgemm_src_kernel<<<dim3(1, 6), 256, 0, stream>>>(
        fluxr, fluxi, 384, Ws_re + l * DD, Ws_im + l * DD, 384,
        Wg + l * 384, Gv, SGr, SGi, 384, 48, 384);
    pscan_fused_kernel<<<1536, 256, 0, stream>>>(eig, Gv, SGr, SGi, opfr, opfi, opdr, opdi, xnp);
    gemm_kernel<64, 0><<<dim3(96, 12), 256, 0, stream>>>(xnp, Eit, 768, 768, df, nullptr, nullptr, nullptr);
    ln_kernel<false><<<12288, 192, 0, stream>>>(df, nt_g + l * 768, nt_b + l * 768, xnp);
    for (int ch = 0; ch < 2; ++ch) {
      gemm_kernel<128, 1><<<dim3(96, 12), 256, 0, stream>>>(
          xnp, W1t + (size_t)ch * 1179648, 768, 1536, nullptr, h1b, nullptr, nullptr);
      if (ch == 0) {
        gemm_kernel<64, 4><<<dim3(96, 12), 256, 0, stream>>>(
            h1b, W2t, 1536, 768, z, nullptr, nullptr, df);
      } else if (l < 3) {
        gemm_kernel<64, 2><<<dim3(96, 12), 256, 0, stream>>>(
            h1b, W2t + 1179648, 1536, 768, z, nullptr, nullptr, nullptr);
      } else {
        gemm_kernel<64, 5><<<dim3(96, 12), 256, 0, stream>>>(
            h1b, W2t + 1179648, 1536, 768, z, zb, nullptr, nullptr);
      }
    }
  }

  gemm_kernel<64, 3><<<dim3(96, 16), 256, 0, stream>>>(zb, dwt, 768, 0, out, nullptr, dec_b, nullptr);
}

// Round 8
// 2806.040 us; speedup vs baseline: 1.1795x; 1.1795x over previous
//
#include <hip/hip_runtime.h>
#include <cstddef>
#include <cstdint>

typedef unsigned short u16;
typedef short bf16x8 __attribute__((ext_vector_type(8)));
typedef float f32x4 __attribute__((ext_vector_type(4)));

__device__ __forceinline__ float gelu_tanh(float x) {
  float x3 = x * x * x;
  float t = tanhf(0.7978845608028654f * (x + 0.044715f * x3));
  return 0.5f * x * (1.0f + t);
}
__device__ __forceinline__ float softplus_f(float x) {
  return (x > 20.0f) ? x : log1pf(expf(x));
}
__device__ __forceinline__ u16 f2bf(float f) {
  uint32_t u = __float_as_uint(f);
  uint32_t r = (u + 0x7fffu + ((u >> 16) & 1u)) >> 16;
  return (u16)r;
}
__device__ __forceinline__ float bf2f(u16 v) {
  return __uint_as_float(((uint32_t)v) << 16);
}

// async global->LDS, 16B/lane; LDS dest = wave-uniform base + lane*16
__device__ __forceinline__ void gload16(const u16* g, u16* l) {
  __builtin_amdgcn_global_load_lds(
      (const __attribute__((address_space(1))) void*)g,
      (__attribute__((address_space(3))) void*)l, 16, 0, 0);
}

// ==================== unified MFMA GEMM, 128xTN tile, two-panel BK=64 ====================
// A [M][K] bf16 row-major; Bt [N][K] bf16.
// MODE 0: Cf = v              MODE 1: Cb = bf16(gelu(v))
// MODE 2: Cf += v             MODE 3: decoder scatter out = v + bias
// MODE 4: Cf += v + bf2f(Db)  MODE 5: Cf += v; Cb = bf16(Cf)
// MODE 6: Cb = bf16(v)
template <int TN, int MODE>
__global__ __launch_bounds__(256) void gemm_kernel(
    const u16* __restrict__ A, const u16* __restrict__ Bt, int K, int ldc,
    float* __restrict__ Cf, u16* __restrict__ Cb,
    const float* __restrict__ bias, const u16* __restrict__ Db) {
  __shared__ u16 As[2][128 * 32];
  __shared__ u16 Bs[2][TN * 32];
  constexpr int NI = (TN == 64) ? 2 : 4;
  const int m0 = blockIdx.x * 128, n0 = blockIdx.y * TN;
  const int tid = threadIdx.x;
  const int lane = tid & 63, w = tid >> 6;
  const int lane15 = lane & 15, quad = lane >> 4;
  const int r0 = lane >> 2, e0 = (lane & 3) * 8;
  const int wy = (TN == 64) ? w : (w >> 1);
  const int wx = (TN == 64) ? 0 : (w & 1);

  const u16* ag0 = A + (size_t)(m0 + w * 32 + r0) * K + e0;
  const u16* ag1 = ag0 + (size_t)16 * K;
  const u16* bg0 = (TN == 64) ? Bt + (size_t)(n0 + w * 16 + r0) * K + e0
                              : Bt + (size_t)(n0 + w * 32 + r0) * K + e0;
  const u16* bg1 = bg0 + (size_t)16 * K;

  f32x4 acc[NI][4] = {};
  const int abase = (wy * (16 * NI) + lane15) * 32 + quad * 8;
  const int bbase = (wx * 64 + lane15) * 32 + quad * 8;

  for (int k0 = 0; k0 < K; k0 += 64) {
#pragma unroll
    for (int p = 0; p < 2; ++p) {
      const int kk = k0 + 32 * p;
      gload16(ag0 + kk, &As[p][w * 1024]);
      gload16(ag1 + kk, &As[p][w * 1024 + 512]);
      if (TN == 64) {
        gload16(bg0 + kk, &Bs[p][w * 512]);
      } else {
        gload16(bg0 + kk, &Bs[p][w * 1024]);
        gload16(bg1 + kk, &Bs[p][w * 1024 + 512]);
      }
    }
    __syncthreads();
#pragma unroll
    for (int p = 0; p < 2; ++p) {
      bf16x8 af[NI], bf[4];
#pragma unroll
      for (int i = 0; i < NI; ++i) af[i] = *(const bf16x8*)&As[p][abase + i * 16 * 32];
#pragma unroll
      for (int j = 0; j < 4; ++j) bf[j] = *(const bf16x8*)&Bs[p][bbase + j * 16 * 32];
#pragma unroll
      for (int i = 0; i < NI; ++i)
#pragma unroll
        for (int j = 0; j < 4; ++j)
          acc[i][j] = __builtin_amdgcn_mfma_f32_16x16x32_bf16(af[i], bf[j], acc[i][j], 0, 0, 0);
    }
    __syncthreads();
  }

  const int mw = m0 + wy * (16 * NI), nw = n0 + wx * 64;
#pragma unroll
  for (int i = 0; i < NI; ++i) {
#pragma unroll
    for (int j = 0; j < 4; ++j) {
      const int col = nw + j * 16 + lane15;
#pragma unroll
      for (int r = 0; r < 4; ++r) {
        const int row = mw + i * 16 + quad * 4 + r;
        const float v = acc[i][j][r];
        const size_t idx = (size_t)row * ldc + col;
        if (MODE == 0) {
          Cf[idx] = v;
        } else if (MODE == 1) {
          Cb[idx] = f2bf(gelu_tanh(v));
        } else if (MODE == 2) {
          Cf[idx] += v;
        } else if (MODE == 3) {
          const int frame = row >> 8, pix = row & 255;
          const int hp = pix >> 4, wp = pix & 15;
          const int co = col >> 8, p1 = (col >> 4) & 15, p2 = col & 15;
          Cf[(((size_t)frame * 4 + co) * 256 + hp * 16 + p1) * 256 + wp * 16 + p2] = v + bias[col];
        } else if (MODE == 4) {
          Cf[idx] += v + bf2f(Db[idx]);
        } else if (MODE == 5) {
          const float nz = Cf[idx] + v;
          Cf[idx] = nz;
          Cb[idx] = f2bf(nz);
        } else if (MODE == 6) {
          Cb[idx] = f2bf(v);
        }
      }
    }
  }
}

// ==================== conv3x3 implicit-GEMM, 128x128 tile, two-panel BK=64 ====================
// (round-5 proven version: grid (96,6), full 9-tap K, fused z+= / zb epilogue)
__global__ __launch_bounds__(256) void conv_mfma_kernel(
    const u16* __restrict__ xnp, const u16* __restrict__ Btc,
    const float* __restrict__ cbias,
    float* __restrict__ z, u16* __restrict__ zb) {
  __shared__ u16 As[2][128 * 32];
  __shared__ u16 Bs[2][128 * 32];
  const int m0 = blockIdx.x * 128, n0 = blockIdx.y * 128;
  const int tid = threadIdx.x;
  const int lane = tid & 63, w = tid >> 6;
  const int lane15 = lane & 15, quad = lane >> 4;
  const int r0 = lane >> 2, e0 = (lane & 3) * 8;

  const int rowA0 = m0 + w * 32 + r0, rowA1 = rowA0 + 16;
  const long long cen0 = ((long long)(rowA0 >> 8) * 324 + ((((rowA0 & 255) >> 4) + 1) * 18) + (rowA0 & 15) + 1) * 768 + e0;
  const long long cen1 = ((long long)(rowA1 >> 8) * 324 + ((((rowA1 & 255) >> 4) + 1) * 18) + (rowA1 & 15) + 1) * 768 + e0;
  const u16* bg0 = Btc + (size_t)(n0 + w * 32 + r0) * 6912 + e0;
  const u16* bg1 = bg0 + (size_t)16 * 6912;

  f32x4 acc[4][4] = {};
  const int wy = w >> 1, wx = w & 1;
  const int abase = (wy * 64 + lane15) * 32 + quad * 8;
  const int bbase = (wx * 64 + lane15) * 32 + quad * 8;

  for (int tap = 0; tap < 9; ++tap) {
    const int doff = ((tap / 3 - 1) * 18 + (tap % 3 - 1)) * 768;
    const u16* a0 = xnp + cen0 + doff;
    const u16* a1 = xnp + cen1 + doff;
    const u16* b0 = bg0 + tap * 768;
    const u16* b1 = bg1 + tap * 768;
    for (int kc = 0; kc < 768; kc += 64) {
#pragma unroll
      for (int p = 0; p < 2; ++p) {
        const int kk = kc + 32 * p;
        gload16(a0 + kk, &As[p][w * 1024]);
        gload16(a1 + kk, &As[p][w * 1024 + 512]);
        gload16(b0 + kk, &Bs[p][w * 1024]);
        gload16(b1 + kk, &Bs[p][w * 1024 + 512]);
      }
      __syncthreads();
#pragma unroll
      for (int p = 0; p < 2; ++p) {
        bf16x8 af[4], bf[4];
#pragma unroll
        for (int i = 0; i < 4; ++i) af[i] = *(const bf16x8*)&As[p][abase + i * 16 * 32];
#pragma unroll
        for (int j = 0; j < 4; ++j) bf[j] = *(const bf16x8*)&Bs[p][bbase + j * 16 * 32];
#pragma unroll
        for (int i = 0; i < 4; ++i)
#pragma unroll
          for (int j = 0; j < 4; ++j)
            acc[i][j] = __builtin_amdgcn_mfma_f32_16x16x32_bf16(af[i], bf[j], acc[i][j], 0, 0, 0);
      }
      __syncthreads();
    }
  }

  const int mw = m0 + wy * 64, nw = n0 + wx * 64;
#pragma unroll
  for (int i = 0; i < 4; ++i) {
#pragma unroll
    for (int j = 0; j < 4; ++j) {
      const int col = nw + j * 16 + lane15;
      const float bv = cbias[col];
#pragma unroll
      for (int r = 0; r < 4; ++r) {
        const int row = mw + i * 16 + quad * 4 + r;
        const size_t idx = (size_t)row * 768 + col;
        const float nz = z[idx] + acc[i][j][r] + bv;
        z[idx] = nz;
        zb[idx] = f2bf(nz);
      }
    }
  }
}

// ==================== encoder: patch-embed MFMA (fp32->bf16 staging, runs once) ====================
__global__ __launch_bounds__(256) void encoder_mfma_kernel(
    const float* __restrict__ x, const float* __restrict__ ew,
    const float* __restrict__ eb, float* __restrict__ z) {
  __shared__ u16 As[128 * 32];
  __shared__ u16 Bs[128 * 32];
  const int m0 = blockIdx.x * 128, n0 = blockIdx.y * 128;
  const int tid = threadIdx.x;
  const int lane = tid & 63, w = tid >> 6;
  const int lane15 = lane & 15, quad = lane >> 4;
  const int srow = tid >> 1, half = tid & 1;
  const int arow = m0 + srow;
  const int frame = arow >> 8, pix = arow & 255, hh = pix >> 4, ww = pix & 15;

  f32x4 acc[4][4] = {};
  const int wy = w >> 1, wx = w & 1;
  const int ar_base = (wy * 64 + lane15) * 32 + quad * 8;
  const int br_base = (wx * 64 + lane15) * 32 + quad * 8;

  for (int k0 = 0; k0 < 1024; k0 += 32) {
    const int gk = k0 + half * 16;
    const int c = gk >> 8, ph = (gk >> 4) & 15;
    const float* ax = x + (((size_t)(frame * 4 + c) * 256 + hh * 16 + ph) * 256 + ww * 16);
    const float* bx = ew + (size_t)(n0 + srow) * 1024 + gk;
    u16 ta[16], tb[16];
#pragma unroll
    for (int j = 0; j < 4; ++j) {
      const float4 va = *(const float4*)(ax + j * 4);
      const float4 vb = *(const float4*)(bx + j * 4);
      ta[j * 4 + 0] = f2bf(va.x); ta[j * 4 + 1] = f2bf(va.y);
      ta[j * 4 + 2] = f2bf(va.z); ta[j * 4 + 3] = f2bf(va.w);
      tb[j * 4 + 0] = f2bf(vb.x); tb[j * 4 + 1] = f2bf(vb.y);
      tb[j * 4 + 2] = f2bf(vb.z); tb[j * 4 + 3] = f2bf(vb.w);
    }
    __syncthreads();
    *(uint4*)&As[srow * 32 + half * 16] = *(uint4*)ta;
    *(uint4*)&As[srow * 32 + half * 16 + 8] = *(uint4*)(ta + 8);
    *(uint4*)&Bs[srow * 32 + half * 16] = *(uint4*)tb;
    *(uint4*)&Bs[srow * 32 + half * 16 + 8] = *(uint4*)(tb + 8);
    __syncthreads();
    bf16x8 af[4], bfv[4];
#pragma unroll
    for (int i = 0; i < 4; ++i) af[i] = *(const bf16x8*)&As[ar_base + i * 16 * 32];
#pragma unroll
    for (int j = 0; j < 4; ++j) bfv[j] = *(const bf16x8*)&Bs[br_base + j * 16 * 32];
#pragma unroll
    for (int i = 0; i < 4; ++i)
#pragma unroll
      for (int j = 0; j < 4; ++j)
        acc[i][j] = __builtin_amdgcn_mfma_f32_16x16x32_bf16(af[i], bfv[j], acc[i][j], 0, 0, 0);
  }

  const int mw = m0 + wy * 64, nw = n0 + wx * 64;
#pragma unroll
  for (int i = 0; i < 4; ++i)
#pragma unroll
    for (int j = 0; j < 4; ++j) {
      const int col = nw + j * 16 + lane15;
      const float bv = eb[col];
#pragma unroll
      for (int r = 0; r < 4; ++r) {
        const int row = mw + i * 16 + quad * 4 + r;
        z[(size_t)row * 768 + col] = acc[i][j][r] + bv;
      }
    }
}

// ==================== weight prep ====================
__global__ __launch_bounds__(256) void expand_kernel(
    const float* __restrict__ Wre, const float* __restrict__ Wim,
    int ldw, int Kc, int Nc, u16* __restrict__ Wt) {
  __shared__ float tile[32][33];
  const int k0 = blockIdx.x * 32, n0 = blockIdx.y * 32;
  const bool khi = k0 >= Kc, nhi = n0 >= Nc;
  const float* src = (khi != nhi) ? Wim : Wre;
  const float sgn = (!nhi && khi) ? -1.0f : 1.0f;
  const int sk = k0 - (khi ? Kc : 0), sn = n0 - (nhi ? Nc : 0);
  const int c = threadIdx.x & 31, r8 = threadIdx.x >> 5;
  for (int r = r8; r < 32; r += 8)
    tile[r][c] = src[(size_t)(sk + r) * ldw + sn + c];
  __syncthreads();
  const int twoK = 2 * Kc;
  for (int r = r8; r < 32; r += 8)
    Wt[(size_t)(n0 + r) * twoK + k0 + c] = f2bf(sgn * tile[c][r]);
}

__global__ __launch_bounds__(256) void reorder_cw_kernel(
    const float* __restrict__ cwl, u16* __restrict__ Btc) {
  __shared__ float buf[6912];
  const int o = blockIdx.x;
  const float* src = cwl + (size_t)o * 6912;
  for (int i = threadIdx.x; i < 6912; i += 256) buf[i] = src[i];
  __syncthreads();
  u16* dst = Btc + (size_t)o * 6912;
  for (int i = threadIdx.x; i < 6912; i += 256) {
    const int tap = i / 768, cc = i - tap * 768;
    dst[i] = f2bf(buf[cc * 9 + tap]);
  }
}

__global__ __launch_bounds__(256) void cast_bf16_kernel(
    const float* __restrict__ in, u16* __restrict__ out, int n) {
  const int g = blockIdx.x * 256 + threadIdx.x;
  if (g < n) out[g] = f2bf(in[g]);
}

// ==================== LayerNorm fp32-in (halo writer) ====================
__global__ __launch_bounds__(192) void ln_kernel(
    const float* __restrict__ in, const float* __restrict__ g,
    const float* __restrict__ b, u16* __restrict__ out) {
  const int row = blockIdx.x, tid = threadIdx.x;
  const float4 v = *(const float4*)(in + (size_t)row * 768 + tid * 4);
  float s = v.x + v.y + v.z + v.w;
  float q = v.x * v.x + v.y * v.y + v.z * v.z + v.w * v.w;
#pragma unroll
  for (int off = 32; off > 0; off >>= 1) {
    s += __shfl_down(s, off);
    q += __shfl_down(q, off);
  }
  __shared__ float rs[3], rq[3];
  if ((tid & 63) == 0) { rs[tid >> 6] = s; rq[tid >> 6] = q; }
  __syncthreads();
  const float S = rs[0] + rs[1] + rs[2], Q = rq[0] + rq[1] + rq[2];
  const float mean = S * (1.0f / 768.0f);
  const float inv = rsqrtf(Q * (1.0f / 768.0f) - mean * mean + 1e-5f);
  const float4 gv = *(const float4*)(g + tid * 4);
  const float4 bv = *(const float4*)(b + tid * 4);
  u16 p[4];
  p[0] = f2bf((v.x - mean) * inv * gv.x + bv.x);
  p[1] = f2bf((v.y - mean) * inv * gv.y + bv.y);
  p[2] = f2bf((v.z - mean) * inv * gv.z + bv.z);
  p[3] = f2bf((v.w - mean) * inv * gv.w + bv.w);
  const int f = row >> 8, pp = row & 255, h = pp >> 4, ww = pp & 15;
  const size_t base = ((size_t)f * 324 + (h + 1) * 18 + ww + 1) * 768;
  *(uint2*)(out + base + tid * 4) = *(uint2*)p;
}

// ==================== LayerNorm bf16-in (flat writer) ====================
__global__ __launch_bounds__(192) void ln_bf_kernel(
    const u16* __restrict__ in, const float* __restrict__ g,
    const float* __restrict__ b, u16* __restrict__ out) {
  const int row = blockIdx.x, tid = threadIdx.x;
  const uint2 raw = *(const uint2*)(in + (size_t)row * 768 + tid * 4);
  const u16* rp = (const u16*)&raw;
  const float v0 = bf2f(rp[0]), v1 = bf2f(rp[1]), v2 = bf2f(rp[2]), v3 = bf2f(rp[3]);
  float s = v0 + v1 + v2 + v3;
  float q = v0 * v0 + v1 * v1 + v2 * v2 + v3 * v3;
#pragma unroll
  for (int off = 32; off > 0; off >>= 1) {
    s += __shfl_down(s, off);
    q += __shfl_down(q, off);
  }
  __shared__ float rs[3], rq[3];
  if ((tid & 63) == 0) { rs[tid >> 6] = s; rq[tid >> 6] = q; }
  __syncthreads();
  const float S = rs[0] + rs[1] + rs[2], Q = rq[0] + rq[1] + rq[2];
  const float mean = S * (1.0f / 768.0f);
  const float inv = rsqrtf(Q * (1.0f / 768.0f) - mean * mean + 1e-5f);
  const float4 gv = *(const float4*)(g + tid * 4);
  const float4 bv = *(const float4*)(b + tid * 4);
  u16 p[4];
  p[0] = f2bf((v0 - mean) * inv * gv.x + bv.x);
  p[1] = f2bf((v1 - mean) * inv * gv.y + bv.y);
  p[2] = f2bf((v2 - mean) * inv * gv.z + bv.z);
  p[3] = f2bf((v3 - mean) * inv * gv.w + bv.w);
  *(uint2*)(out + (size_t)row * 768 + tid * 4) = *(uint2*)p;
}

// ==================== mean over 256 pixels (bf16 in) ====================
__global__ __launch_bounds__(768) void mean_kernel(
    const u16* __restrict__ eig, float* __restrict__ mr, float* __restrict__ mi) {
  const int f = blockIdx.x, c = threadIdx.x;
  const u16* p = eig + (size_t)f * 256 * 768 + c;
  float s0 = 0.f, s1 = 0.f, s2 = 0.f, s3 = 0.f;
  for (int px = 0; px < 256; px += 4) {
    s0 += bf2f(p[(size_t)px * 768]);
    s1 += bf2f(p[(size_t)(px + 1) * 768]);
    s2 += bf2f(p[(size_t)(px + 2) * 768]);
    s3 += bf2f(p[(size_t)(px + 3) * 768]);
  }
  const float tot = (s0 + s1 + s2 + s3) * (1.0f / 256.0f);
  if (c < 384) mr[f * 384 + c] = tot;
  else         mi[f * 384 + c - 384] = tot;
}

// ==================== flux scan + operator precompute ====================
__global__ __launch_bounds__(384) void flux_kernel(
    const float* __restrict__ dt, const float* __restrict__ lamf,
    const float* __restrict__ nu, const float* __restrict__ omega,
    const float* __restrict__ mr, const float* __restrict__ mi,
    float* __restrict__ fluxr, float* __restrict__ fluxi,
    float* __restrict__ opdr, float* __restrict__ opdi,
    float* __restrict__ opfr, float* __restrict__ opfi) {
  const int b = blockIdx.x;
  const int d = threadIdx.x;
  const float sp = softplus_f(lamf[d]);
  float lre = -softplus_f(nu[d]);
  lre = fmaxf(lre, -5.0f);
  const float lim = omega[d];
  const float den = lre * lre + lim * lim;
  float fr = 0.f, fi = 0.f;
  for (int t = 0; t < 12; ++t) {
    const float dtv = dt[b * 12 + t];
    const int idx = (b * 12 + t) * 384 + d;
    const float A = expf(-sp * dtv);
    fr = A * fr + mr[idx] * dtv;
    fi = A * fi + mi[idx] * dtv;
    fluxr[idx] = fr; fluxi[idx] = fi;
    const float ed = expf(lre * dtv);
    const float odr = ed * cosf(lim * dtv);
    const float odi = ed * sinf(lim * dtv);
    opdr[idx] = odr; opdi[idx] = odi;
    const float nr_ = odr - 1.0f, ni_ = odi;
    opfr[idx] = (nr_ * lre + ni_ * lim) / den;
    opfi[idx] = (ni_ * lre - nr_ * lim) / den;
  }
}

// ==================== small fp32 complex GEMM + gate-product epilogue ====================
#define SBM 64
#define SBN 64
#define SBK 32
__global__ __launch_bounds__(256) void cgemm_src_kernel(
    const float* __restrict__ Ar, const float* __restrict__ Ai, int lda,
    const float* __restrict__ Wr, const float* __restrict__ Wi, int ldw,
    const float* __restrict__ Wg,
    float* __restrict__ G, float* __restrict__ SGr, float* __restrict__ SGi,
    int ldc, int M, int K) {
  __shared__ float Asr[SBK][SBM], Asi[SBK][SBM];
  __shared__ float Wsr[SBK][SBN], Wsi[SBK][SBN];
  const int m0 = blockIdx.x * SBM;
  const int n0 = blockIdx.y * SBN;
  const int tid = threadIdx.x;
  const int tn = tid & 15, tm = tid >> 4;
  float accr[4][4] = {}, acci[4][4] = {};
  for (int k0 = 0; k0 < K; k0 += SBK) {
    for (int s = tid; s < 512; s += 256) {
      {
        int r = s >> 3, kk = (s & 7) << 2;
        int row = m0 + r;
        float4 vr = {0.f, 0.f, 0.f, 0.f}, vi = {0.f, 0.f, 0.f, 0.f};
        if (row < M) {
          vr = *(const float4*)(Ar + (size_t)row * lda + k0 + kk);
          vi = *(const float4*)(Ai + (size_t)row * lda + k0 + kk);
        }
        Asr[kk + 0][r] = vr.x; Asr[kk + 1][r] = vr.y; Asr[kk + 2][r] = vr.z; Asr[kk + 3][r] = vr.w;
        Asi[kk + 0][r] = vi.x; Asi[kk + 1][r] = vi.y; Asi[kk + 2][r] = vi.z; Asi[kk + 3][r] = vi.w;
      }
      {
        int wr_ = s >> 4, wc = (s & 15) << 2;
        *(float4*)&Wsr[wr_][wc] = *(const float4*)(Wr + (size_t)(k0 + wr_) * ldw + n0 + wc);
        *(float4*)&Wsi[wr_][wc] = *(const float4*)(Wi + (size_t)(k0 + wr_) * ldw + n0 + wc);
      }
    }
    __syncthreads();
#pragma unroll
    for (int kk = 0; kk < SBK; ++kk) {
      float4 ar4 = *(const float4*)&Asr[kk][tm << 2];
      float4 ai4 = *(const float4*)&Asi[kk][tm << 2];
      float4 wr4 = *(const float4*)&Wsr[kk][tn << 2];
      float4 wi4 = *(const float4*)&Wsi[kk][tn << 2];
      float ar[4] = {ar4.x, ar4.y, ar4.z, ar4.w};
      float ai[4] = {ai4.x, ai4.y, ai4.z, ai4.w};
      float wr[4] = {wr4.x, wr4.y, wr4.z, wr4.w};
      float wi[4] = {wi4.x, wi4.y, wi4.z, wi4.w};
#pragma unroll
      for (int i = 0; i < 4; ++i)
#pragma unroll
        for (int j = 0; j < 4; ++j) {
          accr[i][j] = fmaf(ar[i], wr[j], accr[i][j]);
          accr[i][j] = fmaf(-ai[i], wi[j], accr[i][j]);
          acci[i][j] = fmaf(ar[i], wi[j], acci[i][j]);
          acci[i][j] = fmaf(ai[i], wr[j], acci[i][j]);
        }
    }
    __syncthreads();
  }
#pragma unroll
  for (int i = 0; i < 4; ++i) {
    int row = m0 + (tm << 2) + i;
    if (row >= M) continue;
#pragma unroll
    for (int j = 0; j < 4; ++j) {
      int col = n0 + (tn << 2) + j;
      size_t idx = (size_t)row * ldc + col;
      const float gate = 1.0f / (1.0f + expf(-Ar[idx] * Wg[col]));
      G[idx] = gate;
      SGr[idx] = accr[i][j] * (1.0f - gate);
      SGi[idx] = acci[i][j] * (1.0f - gate);
    }
  }
}

// ==================== fused forcing + u_out pscan (bf16 in) -> bf16 ub ====================
__global__ __launch_bounds__(256) void pscan_fused_kernel(
    const u16* __restrict__ eig,
    const float* __restrict__ Gv,
    const float* __restrict__ SGr, const float* __restrict__ SGi,
    const float* __restrict__ opfr, const float* __restrict__ opfi,
    const float* __restrict__ opdr, const float* __restrict__ opdi,
    u16* __restrict__ ub) {
  const int g = blockIdx.x * 256 + threadIdx.x;
  if (g >= 4 * 256 * 384) return;
  const int d = g % 384;
  const int pix = (g / 384) & 255;
  const int b = g / (384 * 256);
  float ur = 0.f, ui = 0.f;
  for (int t = 0; t < 12; ++t) {
    const int frame = b * 12 + t;
    const size_t idx = ((size_t)frame * 256 + pix) * 768 + d;
    const int fidx = frame * 384 + d;
    const float G = Gv[fidx];
    const float fr = bf2f(eig[idx]) * G + SGr[fidx];
    const float fi = bf2f(eig[idx + 384]) * G + SGi[fidx];
    const float pr = opfr[fidx], pi = opfi[fidx];
    const float utr = fr * pr - fi * pi;
    const float uti = fr * pi + fi * pr;
    const float ar = opdr[fidx], ai = opdi[fidx];
    const float nr = ar * ur - ai * ui + utr;
    const float ni = ar * ui + ai * ur + uti;
    ub[idx] = f2bf(nr); ub[idx + 384] = f2bf(ni);
    ur = nr; ui = ni;
  }
}

extern "C" void kernel_launch(void* const* d_in, const int* in_sizes, int n_in,
                              void* d_out, int out_size, void* d_ws, size_t ws_size,
                              hipStream_t stream) {
  const float* x        = (const float*)d_in[0];
  const float* dt       = (const float*)d_in[1];
  const float* enc_w    = (const float*)d_in[2];
  const float* enc_b    = (const float*)d_in[3];
  const float* ns_g     = (const float*)d_in[4];
  const float* ns_b     = (const float*)d_in[5];
  const float* cw       = (const float*)d_in[6];
  const float* cb       = (const float*)d_in[7];
  const float* nt_g     = (const float*)d_in[8];
  const float* nt_b     = (const float*)d_in[9];
  const float* E_re     = (const float*)d_in[10];
  const float* E_im     = (const float*)d_in[11];
  const float* Ei_re    = (const float*)d_in[12];
  const float* Ei_im    = (const float*)d_in[13];
  const float* lam_flux = (const float*)d_in[14];
  const float* Ws_re    = (const float*)d_in[15];
  const float* Ws_im    = (const float*)d_in[16];
  const float* Wg       = (const float*)d_in[17];
  const float* nu       = (const float*)d_in[18];
  const float* omega    = (const float*)d_in[19];
  const float* w1_re    = (const float*)d_in[20];
  const float* w1_im    = (const float*)d_in[21];
  const float* w2_re    = (const float*)d_in[22];
  const float* w2_im    = (const float*)d_in[23];
  const float* dec_w    = (const float*)d_in[24];
  const float* dec_b    = (const float*)d_in[25];
  float* out = (float*)d_out;

  const size_t NPF = 12288ull * 768;        // 9,437,184
  const size_t XNP = 48ull * 324 * 768;     // halo-padded plane
  const size_t SM = 48ull * 384;

  float* z    = (float*)d_ws;                // [12288][768] fp32 residual master
  float* eigf = z + NPF;                     // region A (NPF floats)
  float* dff  = eigf + NPF;                  // region B (NPF floats)
  u16* xnp    = (u16*)(dff + NPF);           // halo xnbp / flat xnb / ub
  u16* Btc    = xnp + XNP;                   // [768][6912]
  u16* Et     = Btc + 5308416;               // [768][768]
  u16* Eit    = Et + 589824;
  u16* W1t    = Eit + 589824;                // 2 chunks x [1536][768]
  u16* W2t    = W1t + 2359296;               // 2 chunks x [768][1536]
  u16* dwt    = W2t + 2359296;               // [1024][768]
  float* sm   = (float*)(dwt + 786432);
  float* mr    = sm;            float* mi    = mr + SM;
  float* fluxr = mi + SM;       float* fluxi = fluxr + SM;
  float* opdr  = fluxi + SM;    float* opdi  = opdr + SM;
  float* opfr  = opdi + SM;     float* opfi  = opfr + SM;
  float* Gv    = opfi + SM;     float* SGr   = Gv + SM;
  float* SGi   = SGr + SM;

  const size_t need = ((char*)(SGi + SM)) - ((char*)d_ws);
  if (ws_size < need) return;

  // region A: eig_b (bf16, first half) / h1b (bf16 FFN chunk, full region; disjoint lifetime)
  u16* eig_b = (u16*)eigf;
  u16* h1b   = (u16*)eigf;
  // region B: df_b (bf16, first half) + zbuf (bf16, second half)
  u16* df_b  = (u16*)dff;
  u16* zbuf  = (u16*)dff + NPF;

  cast_bf16_kernel<<<(786432 + 255) / 256, 256, 0, stream>>>(dec_w, dwt, 786432);
  encoder_mfma_kernel<<<dim3(96, 6), 256, 0, stream>>>(x, enc_w, enc_b, z);

  for (int l = 0; l < 4; ++l) {
    const size_t DD = 384ull * 384, DF = 384ull * 1536;
    hipMemsetAsync(xnp, 0, XNP * sizeof(u16), stream);  // zero halo borders
    reorder_cw_kernel<<<768, 256, 0, stream>>>(cw + (size_t)l * 768 * 768 * 9, Btc);
    expand_kernel<<<dim3(24, 24), 256, 0, stream>>>(E_re + l * DD, E_im + l * DD, 384, 384, 384, Et);
    expand_kernel<<<dim3(24, 24), 256, 0, stream>>>(Ei_re + l * DD, Ei_im + l * DD, 384, 384, 384, Eit);
    for (int ch = 0; ch < 2; ++ch) {
      expand_kernel<<<dim3(24, 48), 256, 0, stream>>>(
          w1_re + l * DF + ch * 768, w1_im + l * DF + ch * 768, 1536, 384, 768, W1t + (size_t)ch * 1179648);
      expand_kernel<<<dim3(48, 24), 256, 0, stream>>>(
          w2_re + l * DF + (size_t)ch * 768 * 384, w2_im + l * DF + (size_t)ch * 768 * 384, 384, 768, 384,
          W2t + (size_t)ch * 1179648);
    }

    ln_kernel<<<12288, 192, 0, stream>>>(z, ns_g + l * 768, ns_b + l * 768, xnp);
    conv_mfma_kernel<<<dim3(96, 6), 256, 0, stream>>>(xnp, Btc, cb + l * 768, z, zbuf);
    gemm_kernel<64, 6><<<dim3(96, 12), 256, 0, stream>>>(zbuf, Et, 768, 768, nullptr, eig_b, nullptr, nullptr);
    mean_kernel<<<48, 768, 0, stream>>>(eig_b, mr, mi);
    flux_kernel<<<4, 384, 0, stream>>>(dt, lam_flux + l * 384, nu + l * 384, omega + l * 384,
                                       mr, mi, fluxr, fluxi, opdr, opdi, opfr, opfi);
    cgemm_src_kernel<<<dim3(1, 6), 256, 0, stream>>>(
        fluxr, fluxi, 384, Ws_re + l * DD, Ws_im + l * DD, 384,
        Wg + l * 384, Gv, SGr, SGi, 384, 48, 384);
    pscan_fused_kernel<<<1536, 256, 0, stream>>>(eig_b, Gv, SGr, SGi, opfr, opfi, opdr, opdi, xnp);
    gemm_kernel<64, 6><<<dim3(96, 12), 256, 0, stream>>>(xnp, Eit, 768, 768, nullptr, df_b, nullptr, nullptr);
    ln_bf_kernel<<<12288, 192, 0, stream>>>(df_b, nt_g + l * 768, nt_b + l * 768, xnp);
    for (int ch = 0; ch < 2; ++ch) {
      gemm_kernel<128, 1><<<dim3(96, 12), 256, 0, stream>>>(
          xnp, W1t + (size_t)ch * 1179648, 768, 1536, nullptr, h1b, nullptr, nullptr);
      if (ch == 0) {
        // z += W2 + df (df-residual fused, bf16 df read)
        gemm_kernel<64, 4><<<dim3(96, 12), 256, 0, stream>>>(
            h1b, W2t, 1536, 768, z, nullptr, nullptr, df_b);
      } else if (l < 3) {
        gemm_kernel<64, 2><<<dim3(96, 12), 256, 0, stream>>>(
            h1b, W2t + 1179648, 1536, 768, z, nullptr, nullptr, nullptr);
      } else {
        // final layer: also emit zbuf for the decoder
        gemm_kernel<64, 5><<<dim3(96, 12), 256, 0, stream>>>(
            h1b, W2t + 1179648, 1536, 768, z, zbuf, nullptr, nullptr);
      }
    }
  }

  gemm_kernel<64, 3><<<dim3(96, 16), 256, 0, stream>>>(zbuf, dwt, 768, 0, out, nullptr, dec_b, nullptr);
}